// Round 9
// baseline (421.046 us; speedup 1.0000x reference)
//
#include <hip/hip_runtime.h>
#include <hip/hip_cooperative_groups.h>

namespace cg = cooperative_groups;

typedef unsigned short ushort_t;
typedef unsigned long long ull_t;

#define B_ 64
#define S_ 512
#define E_ 256
#define H_ 128
#define M_ (B_ * S_)   // 32768 rows
#define CAP_ 128       // max neighbor slots

// ---- Phase A body (produces Ys slab) — identical math to R8 ---------------
template <int K, bool GATHER>
__device__ __forceinline__ void phaseA_body(
        const float* __restrict__ X, const int* __restrict__ sent,
        const float* __restrict__ emb, const float* __restrict__ W,
        float* Ys, float (*Xs)[8 * S_], float (*Wsh)[8 * 32],
        int tid, int colBase, int rowBase) {
    const int r0 = tid >> 1;              // 0..255
    const int kq = (tid & 1) * 4;         // 0 or 4
    const float* xp0;
    const float* xp1;
    if (GATHER) {
        xp0 = emb + (size_t)sent[rowBase + r0]       * K + kq;
        xp1 = emb + (size_t)sent[rowBase + r0 + 256] * K + kq;
    } else {
        xp0 = X + (size_t)(rowBase + r0)       * K + kq;
        xp1 = X + (size_t)(rowBase + r0 + 256) * K + kq;
    }
    const int wcol = (tid >> 1) & 31;
    const float* wp = W + (size_t)(colBase + wcol) * K + kq;

    const int rg4 = tid & ~3;             // 0..508
    const int c0  = (tid & 3) * 8;

    float acc[4][8] = {};
    float4 g0, g1;
    float4 wv = {0.f, 0.f, 0.f, 0.f};

    constexpr int NC = K / 8;

    g0 = *(const float4*)xp0;
    g1 = *(const float4*)xp1;
    if (tid < 64) wv = *(const float4*)wp;
    Xs[0][(kq + 0) * 512 + r0] = g0.x;
    Xs[0][(kq + 1) * 512 + r0] = g0.y;
    Xs[0][(kq + 2) * 512 + r0] = g0.z;
    Xs[0][(kq + 3) * 512 + r0] = g0.w;
    Xs[0][(kq + 0) * 512 + r0 + 256] = g1.x;
    Xs[0][(kq + 1) * 512 + r0 + 256] = g1.y;
    Xs[0][(kq + 2) * 512 + r0 + 256] = g1.z;
    Xs[0][(kq + 3) * 512 + r0 + 256] = g1.w;
    if (tid < 64) {
        Wsh[0][(kq + 0) * 32 + wcol] = wv.x;
        Wsh[0][(kq + 1) * 32 + wcol] = wv.y;
        Wsh[0][(kq + 2) * 32 + wcol] = wv.z;
        Wsh[0][(kq + 3) * 32 + wcol] = wv.w;
    }
    __syncthreads();

    #pragma unroll 1
    for (int c = 0; c < NC; ++c) {
        const int cur = c & 1;
        if (c + 1 < NC) {
            g0 = *(const float4*)(xp0 + (c + 1) * 8);
            g1 = *(const float4*)(xp1 + (c + 1) * 8);
            if (tid < 64) wv = *(const float4*)(wp + (c + 1) * 8);
        }
        #pragma unroll
        for (int k = 0; k < 8; ++k) {
            const float4 xa = *(const float4*)&Xs[cur][k * 512 + rg4];
            const float4 wa = *(const float4*)&Wsh[cur][k * 32 + c0];
            const float4 wb = *(const float4*)&Wsh[cur][k * 32 + c0 + 4];
            const float xv[4]  = {xa.x, xa.y, xa.z, xa.w};
            const float wv8[8] = {wa.x, wa.y, wa.z, wa.w, wb.x, wb.y, wb.z, wb.w};
            #pragma unroll
            for (int i = 0; i < 4; ++i)
                #pragma unroll
                for (int j = 0; j < 8; ++j)
                    acc[i][j] += xv[i] * wv8[j];
        }
        if (c + 1 < NC) {
            const int nb = cur ^ 1;
            Xs[nb][(kq + 0) * 512 + r0] = g0.x;
            Xs[nb][(kq + 1) * 512 + r0] = g0.y;
            Xs[nb][(kq + 2) * 512 + r0] = g0.z;
            Xs[nb][(kq + 3) * 512 + r0] = g0.w;
            Xs[nb][(kq + 0) * 512 + r0 + 256] = g1.x;
            Xs[nb][(kq + 1) * 512 + r0 + 256] = g1.y;
            Xs[nb][(kq + 2) * 512 + r0 + 256] = g1.z;
            Xs[nb][(kq + 3) * 512 + r0 + 256] = g1.w;
            if (tid < 64) {
                Wsh[nb][(kq + 0) * 32 + wcol] = wv.x;
                Wsh[nb][(kq + 1) * 32 + wcol] = wv.y;
                Wsh[nb][(kq + 2) * 32 + wcol] = wv.z;
                Wsh[nb][(kq + 3) * 32 + wcol] = wv.w;
            }
        }
        __syncthreads();
    }

    #pragma unroll
    for (int i = 0; i < 4; ++i) {
        const int r = rg4 + i;
        *(float4*)&Ys[r * 36 + c0]     = make_float4(acc[i][0], acc[i][1], acc[i][2], acc[i][3]);
        *(float4*)&Ys[r * 36 + c0 + 4] = make_float4(acc[i][4], acc[i][5], acc[i][6], acc[i][7]);
    }
}

// ---- Phase B body (consumes Ys slab) — identical math to R8 ---------------
template <bool POOL>
__device__ __forceinline__ void phaseB_body(
        const ushort_t* __restrict__ idxl, const int* __restrict__ nnz,
        const float* __restrict__ invdeg, const float* __restrict__ bias,
        float* __restrict__ out, const float* Ys, float* scratch,
        int tid, int b, int colBase, int rowBase) {
    const int rsub = tid >> 3;     // 0..63
    const int cc   = tid & 7;      // float4 chunk of the 32-col slab
    const float4* Ys4 = (const float4*)Ys;
    const float4 bv = *(const float4*)(bias + colBase + cc * 4);
    float4 pmax = {0.f, 0.f, 0.f, 0.f};

    int grow = rowBase + rsub;
    int n_cur = nnz[grow];
    float inv_cur = invdeg[grow];
    const ushort_t* il = idxl + (size_t)grow * CAP_;
    ull_t pk = *(const ull_t*)il;

    #pragma unroll 1
    for (int p = 0; p < 8; ++p) {
        const int r = p * 64 + rsub;
        int n_nxt = 0; float inv_nxt = 0.f; ull_t pk_nxt = 0;
        const ushort_t* il_nxt = il + 64 * CAP_;
        if (p < 7) {
            n_nxt = nnz[grow + 64];
            inv_nxt = invdeg[grow + 64];
            pk_nxt = *(const ull_t*)il_nxt;
        }
        float4 a = Ys4[r * 9 + cc];
        float4 a2 = {0.f, 0.f, 0.f, 0.f};
        const int n = n_cur;
        int i = 0;
        for (; i + 4 <= n; i += 4) {
            const ull_t pk_p = *(const ull_t*)(il + i + 4);
            const int t0 = (int)(pk & 0xffffu);
            const int t1 = (int)((pk >> 16) & 0xffffu);
            const int t2 = (int)((pk >> 32) & 0xffffu);
            const int t3 = (int)((pk >> 48) & 0xffffu);
            const float4 v0 = Ys4[t0 * 9 + cc];
            const float4 v1 = Ys4[t1 * 9 + cc];
            const float4 v2 = Ys4[t2 * 9 + cc];
            const float4 v3 = Ys4[t3 * 9 + cc];
            a.x += v0.x + v1.x;  a.y += v0.y + v1.y;
            a.z += v0.z + v1.z;  a.w += v0.w + v1.w;
            a2.x += v2.x + v3.x; a2.y += v2.y + v3.y;
            a2.z += v2.z + v3.z; a2.w += v2.w + v3.w;
            pk = pk_p;
        }
        for (; i < n; ++i) {
            const int t = il[i];
            const float4 v = Ys4[t * 9 + cc];
            a.x += v.x; a.y += v.y; a.z += v.z; a.w += v.w;
        }
        a.x += a2.x; a.y += a2.y; a.z += a2.z; a.w += a2.w;
        float4 o;
        o.x = fmaxf((a.x + 2.0f * bv.x) * inv_cur, 0.0f);
        o.y = fmaxf((a.y + 2.0f * bv.y) * inv_cur, 0.0f);
        o.z = fmaxf((a.z + 2.0f * bv.z) * inv_cur, 0.0f);
        o.w = fmaxf((a.w + 2.0f * bv.w) * inv_cur, 0.0f);
        if (!POOL) {
            ((float4*)(out + (size_t)(rowBase + r) * H_ + colBase))[cc] = o;
        } else {
            pmax.x = fmaxf(pmax.x, o.x); pmax.y = fmaxf(pmax.y, o.y);
            pmax.z = fmaxf(pmax.z, o.z); pmax.w = fmaxf(pmax.w, o.w);
        }
        grow += 64; il = il_nxt;
        n_cur = n_nxt; inv_cur = inv_nxt; pk = pk_nxt;
    }

    if (POOL) {
        float4* smax = (float4*)scratch;
        smax[rsub * 8 + cc] = pmax;
        __syncthreads();
        if (tid < 64) {
            const int gg = tid >> 3, c2 = tid & 7;
            float4 m = smax[gg * 8 + c2];
            #pragma unroll
            for (int q = 1; q < 8; ++q) {
                const float4 v = smax[(gg + 8 * q) * 8 + c2];
                m.x = fmaxf(m.x, v.x); m.y = fmaxf(m.y, v.y);
                m.z = fmaxf(m.z, v.z); m.w = fmaxf(m.w, v.w);
            }
            smax[512 + gg * 8 + c2] = m;
        }
        __syncthreads();
        if (tid < 8) {
            float4 m = smax[512 + tid];
            #pragma unroll
            for (int g = 1; g < 8; ++g) {
                const float4 v = smax[512 + g * 8 + tid];
                m.x = fmaxf(m.x, v.x); m.y = fmaxf(m.y, v.y);
                m.z = fmaxf(m.z, v.z); m.w = fmaxf(m.w, v.w);
            }
            ((float4*)(out + (size_t)b * H_ + colBase))[tid] = m;
        }
    }
}

// ---------------------------------------------------------------------------
// The cooperative mega-kernel: adjidx -> L1 -> L2 -> L3+pool -> logits,
// with grid.sync() between phases. 256 blocks (1/CU, all co-resident),
// 512 threads. All per-phase math bit-identical to the R8 kernels.
// ---------------------------------------------------------------------------
__global__ __launch_bounds__(512, 1)
void k_mega(const int* __restrict__ sent, const float* __restrict__ adj,
            const float* __restrict__ emb,
            const float* __restrict__ W1, const float* __restrict__ b1,
            const float* __restrict__ W2, const float* __restrict__ b2,
            const float* __restrict__ W3, const float* __restrict__ b3,
            const float* __restrict__ Wp, const float* __restrict__ bp,
            float* __restrict__ h1, float* __restrict__ h2,
            ushort_t* __restrict__ idxl, int* __restrict__ nnz,
            float* __restrict__ invdeg, float* __restrict__ pooled,
            float* __restrict__ out) {
    __shared__ __align__(16) float Ys[S_ * 36];
    __shared__ __align__(16) float Xs[2][8 * S_];
    __shared__ __align__(16) float Wsh[2][8 * 32];

    cg::grid_group grid = cg::this_grid();
    const int tid = threadIdx.x;
    const int bid = blockIdx.x;

    // ---- phase 0: adjidx (each block owns 128 contiguous rows) ----
    {
        const int wave = tid >> 6, lane = tid & 63;
        #pragma unroll 1
        for (int it = 0; it < 16; ++it) {
            const int row = bid * 128 + wave * 16 + it;
            const float4* arow = (const float4*)(adj + (size_t)row * S_);
            ushort_t* dst = idxl + (size_t)row * CAP_;
            int total = 0;
            #pragma unroll
            for (int c = 0; c < 2; ++c) {
                float4 v = arow[c * 64 + lane];
                float f[4] = {v.x, v.y, v.z, v.w};
                #pragma unroll
                for (int j = 0; j < 4; ++j) {
                    unsigned long long m = __ballot(f[j] != 0.0f);
                    if (f[j] != 0.0f) {
                        int pos = total + __popcll(m & ((1ull << lane) - 1ull));
                        if (pos < CAP_) dst[pos] = (ushort_t)(c * 256 + lane * 4 + j);
                    }
                    total += __popcll(m);
                }
            }
            if (lane == 0) {
                nnz[row] = total < CAP_ ? total : CAP_;
                invdeg[row] = 1.0f / (float)(total + 1);
            }
        }
    }
    grid.sync();

    // ---- block -> (batch, col-group) mapping (R2 geometry) ----
    const int xcd = bid & 7, slot = bid >> 3;
    const int b = xcd + 8 * (slot >> 2);
    const int cgi = slot & 3;
    const int colBase = cgi * 32;
    const int rowBase = b * S_;

    // ---- layer 1 (K=256, emb gather) ----
    phaseA_body<E_, true>(nullptr, sent, emb, W1, Ys, Xs, Wsh, tid, colBase, rowBase);
    __syncthreads();
    phaseB_body<false>(idxl, nnz, invdeg, b1, h1, Ys, (float*)Xs, tid, b, colBase, rowBase);
    grid.sync();

    // ---- layer 2 (K=128) ----
    phaseA_body<H_, false>(h1, nullptr, nullptr, W2, Ys, Xs, Wsh, tid, colBase, rowBase);
    __syncthreads();
    phaseB_body<false>(idxl, nnz, invdeg, b2, h2, Ys, (float*)Xs, tid, b, colBase, rowBase);
    grid.sync();

    // ---- layer 3 (K=128) + in-block max-pool ----
    phaseA_body<H_, false>(h2, nullptr, nullptr, W3, Ys, Xs, Wsh, tid, colBase, rowBase);
    __syncthreads();
    phaseB_body<true>(idxl, nnz, invdeg, b3, pooled, Ys, (float*)Xs, tid, b, colBase, rowBase);
    grid.sync();

    // ---- final logits (cg==0 block of each batch; k_final math) ----
    {
        const int j = tid & 127;
        const bool act = (cgi == 0) && (tid < 128);
        float m  = act ? pooled[(size_t)b * H_ + j] : 0.f;
        float t0 = act ? m * Wp[j]      : 0.f;
        float t1 = act ? m * Wp[H_ + j] : 0.f;
        #pragma unroll
        for (int off = 32; off > 0; off >>= 1) {
            t0 += __shfl_down(t0, off);
            t1 += __shfl_down(t1, off);
        }
        __shared__ float red[2][2];
        const int wave = tid >> 6, lane = tid & 63;
        if (act && lane == 0) { red[0][wave] = t0; red[1][wave] = t1; }
        __syncthreads();
        if (cgi == 0 && tid == 0) out[b * 2 + 0] = red[0][0] + red[0][1] + bp[0];
        if (cgi == 0 && tid == 1) out[b * 2 + 1] = red[1][0] + red[1][1] + bp[1];
    }
}

// ---------------------------------------------------------------------------
extern "C" void kernel_launch(void* const* d_in, const int* in_sizes, int n_in,
                              void* d_out, int out_size, void* d_ws, size_t ws_size,
                              hipStream_t stream) {
    const int*   sent = (const int*)d_in[0];
    const float* adj  = (const float*)d_in[1];
    const float* emb  = (const float*)d_in[2];
    const float* W1   = (const float*)d_in[3];
    const float* b1   = (const float*)d_in[4];
    const float* W2   = (const float*)d_in[5];
    const float* b2   = (const float*)d_in[6];
    const float* W3   = (const float*)d_in[7];
    const float* b3   = (const float*)d_in[8];
    const float* Wp   = (const float*)d_in[9];
    const float* bp   = (const float*)d_in[10];
    float* out = (float*)d_out;

    char* ws = (char*)d_ws;
    float*    h1     = (float*)ws;                              // 16 MiB
    float*    h2     = (float*)(ws + ((size_t)16 << 20));       // 16 MiB
    char*     base   = ws + ((size_t)32 << 20);
    float*    invdeg = (float*)base;                            // M f32
    int*      nnz    = (int*)(base + (size_t)M_ * 4);
    ushort_t* idxl   = (ushort_t*)(base + (size_t)M_ * 8);      // 8 MiB
    float*    pooled = (float*)(base + (size_t)M_ * 8 + (size_t)M_ * CAP_ * 2);

    void* args[] = {
        (void*)&sent, (void*)&adj, (void*)&emb,
        (void*)&W1, (void*)&b1, (void*)&W2, (void*)&b2,
        (void*)&W3, (void*)&b3, (void*)&Wp, (void*)&bp,
        (void*)&h1, (void*)&h2, (void*)&idxl, (void*)&nnz,
        (void*)&invdeg, (void*)&pooled, (void*)&out
    };
    hipLaunchCooperativeKernel((const void*)k_mega, dim3(256), dim3(512),
                               args, 0, stream);
}

// Round 10
// 326.106 us; speedup vs baseline: 1.2911x; 1.2911x over previous
//
#include <hip/hip_runtime.h>

typedef unsigned short ushort_t;
typedef unsigned long long ull_t;

#define B_ 64
#define S_ 512
#define E_ 256
#define H_ 128
#define M_ (B_ * S_)   // 32768 rows
#define CAP_ 128       // max neighbor slots

// ---------------------------------------------------------------------------
// K1: adjidx (unchanged R8 math) + zero the per-batch barrier counters.
// Stream order guarantees counters are 0 before k_mega2 starts.
// ---------------------------------------------------------------------------
__global__ void k_pre(const float* __restrict__ adj,
                      ushort_t* __restrict__ idxl,
                      int* __restrict__ nnz,
                      float* __restrict__ invdeg,
                      int* __restrict__ cnt) {
    if (blockIdx.x == 0 && threadIdx.x < 64) cnt[threadIdx.x] = 0;
    int row  = blockIdx.x * 4 + (threadIdx.x >> 6);
    int lane = threadIdx.x & 63;
    const float4* arow = (const float4*)(adj + (size_t)row * S_);
    ushort_t* dst = idxl + (size_t)row * CAP_;
    int total = 0;
    #pragma unroll
    for (int c = 0; c < 2; ++c) {
        float4 v = arow[c * 64 + lane];
        float f[4] = {v.x, v.y, v.z, v.w};
        #pragma unroll
        for (int j = 0; j < 4; ++j) {
            unsigned long long m = __ballot(f[j] != 0.0f);
            if (f[j] != 0.0f) {
                int pos = total + __popcll(m & ((1ull << lane) - 1ull));
                if (pos < CAP_) dst[pos] = (ushort_t)(c * 256 + lane * 4 + j);
            }
            total += __popcll(m);
        }
    }
    if (lane == 0) {
        nnz[row] = total < CAP_ ? total : CAP_;
        invdeg[row] = 1.0f / (float)(total + 1);
    }
}

// ---- Phase A body (produces Ys slab) — identical math to R8/R9 ------------
template <int K, bool GATHER>
__device__ __forceinline__ void phaseA_body(
        const float* __restrict__ X, const int* __restrict__ sent,
        const float* __restrict__ emb, const float* __restrict__ W,
        float* Ys, float (*Xs)[8 * S_], float (*Wsh)[8 * 32],
        int tid, int colBase, int rowBase) {
    const int r0 = tid >> 1;              // 0..255
    const int kq = (tid & 1) * 4;         // 0 or 4
    const float* xp0;
    const float* xp1;
    if (GATHER) {
        xp0 = emb + (size_t)sent[rowBase + r0]       * K + kq;
        xp1 = emb + (size_t)sent[rowBase + r0 + 256] * K + kq;
    } else {
        xp0 = X + (size_t)(rowBase + r0)       * K + kq;
        xp1 = X + (size_t)(rowBase + r0 + 256) * K + kq;
    }
    const int wcol = (tid >> 1) & 31;
    const float* wp = W + (size_t)(colBase + wcol) * K + kq;

    const int rg4 = tid & ~3;             // 0..508
    const int c0  = (tid & 3) * 8;

    float acc[4][8] = {};
    float4 g0, g1;
    float4 wv = {0.f, 0.f, 0.f, 0.f};

    constexpr int NC = K / 8;

    g0 = *(const float4*)xp0;
    g1 = *(const float4*)xp1;
    if (tid < 64) wv = *(const float4*)wp;
    Xs[0][(kq + 0) * 512 + r0] = g0.x;
    Xs[0][(kq + 1) * 512 + r0] = g0.y;
    Xs[0][(kq + 2) * 512 + r0] = g0.z;
    Xs[0][(kq + 3) * 512 + r0] = g0.w;
    Xs[0][(kq + 0) * 512 + r0 + 256] = g1.x;
    Xs[0][(kq + 1) * 512 + r0 + 256] = g1.y;
    Xs[0][(kq + 2) * 512 + r0 + 256] = g1.z;
    Xs[0][(kq + 3) * 512 + r0 + 256] = g1.w;
    if (tid < 64) {
        Wsh[0][(kq + 0) * 32 + wcol] = wv.x;
        Wsh[0][(kq + 1) * 32 + wcol] = wv.y;
        Wsh[0][(kq + 2) * 32 + wcol] = wv.z;
        Wsh[0][(kq + 3) * 32 + wcol] = wv.w;
    }
    __syncthreads();

    #pragma unroll 1
    for (int c = 0; c < NC; ++c) {
        const int cur = c & 1;
        if (c + 1 < NC) {
            g0 = *(const float4*)(xp0 + (c + 1) * 8);
            g1 = *(const float4*)(xp1 + (c + 1) * 8);
            if (tid < 64) wv = *(const float4*)(wp + (c + 1) * 8);
        }
        #pragma unroll
        for (int k = 0; k < 8; ++k) {
            const float4 xa = *(const float4*)&Xs[cur][k * 512 + rg4];
            const float4 wa = *(const float4*)&Wsh[cur][k * 32 + c0];
            const float4 wb = *(const float4*)&Wsh[cur][k * 32 + c0 + 4];
            const float xv[4]  = {xa.x, xa.y, xa.z, xa.w};
            const float wv8[8] = {wa.x, wa.y, wa.z, wa.w, wb.x, wb.y, wb.z, wb.w};
            #pragma unroll
            for (int i = 0; i < 4; ++i)
                #pragma unroll
                for (int j = 0; j < 8; ++j)
                    acc[i][j] += xv[i] * wv8[j];
        }
        if (c + 1 < NC) {
            const int nb = cur ^ 1;
            Xs[nb][(kq + 0) * 512 + r0] = g0.x;
            Xs[nb][(kq + 1) * 512 + r0] = g0.y;
            Xs[nb][(kq + 2) * 512 + r0] = g0.z;
            Xs[nb][(kq + 3) * 512 + r0] = g0.w;
            Xs[nb][(kq + 0) * 512 + r0 + 256] = g1.x;
            Xs[nb][(kq + 1) * 512 + r0 + 256] = g1.y;
            Xs[nb][(kq + 2) * 512 + r0 + 256] = g1.z;
            Xs[nb][(kq + 3) * 512 + r0 + 256] = g1.w;
            if (tid < 64) {
                Wsh[nb][(kq + 0) * 32 + wcol] = wv.x;
                Wsh[nb][(kq + 1) * 32 + wcol] = wv.y;
                Wsh[nb][(kq + 2) * 32 + wcol] = wv.z;
                Wsh[nb][(kq + 3) * 32 + wcol] = wv.w;
            }
        }
        __syncthreads();
    }

    #pragma unroll
    for (int i = 0; i < 4; ++i) {
        const int r = rg4 + i;
        *(float4*)&Ys[r * 36 + c0]     = make_float4(acc[i][0], acc[i][1], acc[i][2], acc[i][3]);
        *(float4*)&Ys[r * 36 + c0 + 4] = make_float4(acc[i][4], acc[i][5], acc[i][6], acc[i][7]);
    }
}

// ---- Phase B body (consumes Ys slab) — identical math to R8/R9 ------------
template <bool POOL>
__device__ __forceinline__ void phaseB_body(
        const ushort_t* __restrict__ idxl, const int* __restrict__ nnz,
        const float* __restrict__ invdeg, const float* __restrict__ bias,
        float* __restrict__ out, const float* Ys, float* scratch,
        int tid, int b, int colBase, int rowBase) {
    const int rsub = tid >> 3;     // 0..63
    const int cc   = tid & 7;      // float4 chunk of the 32-col slab
    const float4* Ys4 = (const float4*)Ys;
    const float4 bv = *(const float4*)(bias + colBase + cc * 4);
    float4 pmax = {0.f, 0.f, 0.f, 0.f};

    int grow = rowBase + rsub;
    int n_cur = nnz[grow];
    float inv_cur = invdeg[grow];
    const ushort_t* il = idxl + (size_t)grow * CAP_;
    ull_t pk = *(const ull_t*)il;

    #pragma unroll 1
    for (int p = 0; p < 8; ++p) {
        const int r = p * 64 + rsub;
        int n_nxt = 0; float inv_nxt = 0.f; ull_t pk_nxt = 0;
        const ushort_t* il_nxt = il + 64 * CAP_;
        if (p < 7) {
            n_nxt = nnz[grow + 64];
            inv_nxt = invdeg[grow + 64];
            pk_nxt = *(const ull_t*)il_nxt;
        }
        float4 a = Ys4[r * 9 + cc];
        float4 a2 = {0.f, 0.f, 0.f, 0.f};
        const int n = n_cur;
        int i = 0;
        for (; i + 4 <= n; i += 4) {
            const ull_t pk_p = *(const ull_t*)(il + i + 4);
            const int t0 = (int)(pk & 0xffffu);
            const int t1 = (int)((pk >> 16) & 0xffffu);
            const int t2 = (int)((pk >> 32) & 0xffffu);
            const int t3 = (int)((pk >> 48) & 0xffffu);
            const float4 v0 = Ys4[t0 * 9 + cc];
            const float4 v1 = Ys4[t1 * 9 + cc];
            const float4 v2 = Ys4[t2 * 9 + cc];
            const float4 v3 = Ys4[t3 * 9 + cc];
            a.x += v0.x + v1.x;  a.y += v0.y + v1.y;
            a.z += v0.z + v1.z;  a.w += v0.w + v1.w;
            a2.x += v2.x + v3.x; a2.y += v2.y + v3.y;
            a2.z += v2.z + v3.z; a2.w += v2.w + v3.w;
            pk = pk_p;
        }
        for (; i < n; ++i) {
            const int t = il[i];
            const float4 v = Ys4[t * 9 + cc];
            a.x += v.x; a.y += v.y; a.z += v.z; a.w += v.w;
        }
        a.x += a2.x; a.y += a2.y; a.z += a2.z; a.w += a2.w;
        float4 o;
        o.x = fmaxf((a.x + 2.0f * bv.x) * inv_cur, 0.0f);
        o.y = fmaxf((a.y + 2.0f * bv.y) * inv_cur, 0.0f);
        o.z = fmaxf((a.z + 2.0f * bv.z) * inv_cur, 0.0f);
        o.w = fmaxf((a.w + 2.0f * bv.w) * inv_cur, 0.0f);
        if (!POOL) {
            ((float4*)(out + (size_t)(rowBase + r) * H_ + colBase))[cc] = o;
        } else {
            pmax.x = fmaxf(pmax.x, o.x); pmax.y = fmaxf(pmax.y, o.y);
            pmax.z = fmaxf(pmax.z, o.z); pmax.w = fmaxf(pmax.w, o.w);
        }
        grow += 64; il = il_nxt;
        n_cur = n_nxt; inv_cur = inv_nxt; pk = pk_nxt;
    }

    if (POOL) {
        float4* smax = (float4*)scratch;
        smax[rsub * 8 + cc] = pmax;
        __syncthreads();
        if (tid < 64) {
            const int gg = tid >> 3, c2 = tid & 7;
            float4 m = smax[gg * 8 + c2];
            #pragma unroll
            for (int q = 1; q < 8; ++q) {
                const float4 v = smax[(gg + 8 * q) * 8 + c2];
                m.x = fmaxf(m.x, v.x); m.y = fmaxf(m.y, v.y);
                m.z = fmaxf(m.z, v.z); m.w = fmaxf(m.w, v.w);
            }
            smax[512 + gg * 8 + c2] = m;
        }
        __syncthreads();
        if (tid < 8) {
            float4 m = smax[512 + tid];
            #pragma unroll
            for (int g = 1; g < 8; ++g) {
                const float4 v = smax[512 + g * 8 + tid];
                m.x = fmaxf(m.x, v.x); m.y = fmaxf(m.y, v.y);
                m.z = fmaxf(m.z, v.z); m.w = fmaxf(m.w, v.w);
            }
            ((float4*)(out + (size_t)b * H_ + colBase))[tid] = m;
        }
    }
}

// ---- per-batch 4-block barrier (monotonic counter, zeroed by k_pre) -------
__device__ __forceinline__ void batch_bar(int* cnt, int target, int tid) {
    __syncthreads();
    if (tid == 0) {
        __threadfence();   // make this block's h/pooled writes device-visible
        __hip_atomic_fetch_add(cnt, 1, __ATOMIC_ACQ_REL, __HIP_MEMORY_SCOPE_AGENT);
        while (__hip_atomic_load(cnt, __ATOMIC_ACQUIRE, __HIP_MEMORY_SCOPE_AGENT) < target)
            __builtin_amdgcn_s_sleep(8);
        __threadfence();   // acquire: invalidate caches before reading siblings' data
    }
    __syncthreads();
}

// ---------------------------------------------------------------------------
// Mega-kernel: L1 -> bar4 -> L2 -> bar4 -> L3+pool -> bar4 -> logits.
// 256 blocks (1 block/CU via 108.5KB LDS -> all co-resident), 512 threads.
// Siblings of a batch share an XCD (bid&7 mapping) -> barrier lives in
// XCD-local L2. Regular launch: graph-capturable, no cooperative overhead.
// ---------------------------------------------------------------------------
__global__ __launch_bounds__(512, 1)
void k_mega2(const int* __restrict__ sent, const float* __restrict__ emb,
             const float* __restrict__ W1, const float* __restrict__ b1,
             const float* __restrict__ W2, const float* __restrict__ b2,
             const float* __restrict__ W3, const float* __restrict__ b3,
             const float* __restrict__ Wp, const float* __restrict__ bp,
             float* __restrict__ h1, float* __restrict__ h2,
             const ushort_t* __restrict__ idxl, const int* __restrict__ nnz,
             const float* __restrict__ invdeg, float* __restrict__ pooled,
             int* __restrict__ cnt, float* __restrict__ out) {
    __shared__ __align__(16) float Ys[S_ * 36];
    __shared__ __align__(16) float Xs[2][8 * S_];
    __shared__ __align__(16) float Wsh[2][8 * 32];

    const int tid = threadIdx.x;
    const int bid = blockIdx.x;
    const int xcd = bid & 7, slot = bid >> 3;
    const int b = xcd + 8 * (slot >> 2);
    const int cgi = slot & 3;
    const int colBase = cgi * 32;
    const int rowBase = b * S_;
    int* mycnt = cnt + b;

    // ---- layer 1 (K=256, emb gather) ----
    phaseA_body<E_, true>(nullptr, sent, emb, W1, Ys, Xs, Wsh, tid, colBase, rowBase);
    __syncthreads();
    phaseB_body<false>(idxl, nnz, invdeg, b1, h1, Ys, (float*)Xs, tid, b, colBase, rowBase);
    batch_bar(mycnt, 4, tid);

    // ---- layer 2 (K=128) ----
    phaseA_body<H_, false>(h1, nullptr, nullptr, W2, Ys, Xs, Wsh, tid, colBase, rowBase);
    __syncthreads();
    phaseB_body<false>(idxl, nnz, invdeg, b2, h2, Ys, (float*)Xs, tid, b, colBase, rowBase);
    batch_bar(mycnt, 8, tid);

    // ---- layer 3 (K=128) + in-block max-pool ----
    phaseA_body<H_, false>(h2, nullptr, nullptr, W3, Ys, Xs, Wsh, tid, colBase, rowBase);
    __syncthreads();
    phaseB_body<true>(idxl, nnz, invdeg, b3, pooled, Ys, (float*)Xs, tid, b, colBase, rowBase);
    batch_bar(mycnt, 12, tid);

    // ---- final logits (cg==0 block of each batch; k_final math) ----
    {
        const int j = tid & 127;
        const bool act = (cgi == 0) && (tid < 128);
        float m  = act ? pooled[(size_t)b * H_ + j] : 0.f;
        float t0 = act ? m * Wp[j]      : 0.f;
        float t1 = act ? m * Wp[H_ + j] : 0.f;
        #pragma unroll
        for (int off = 32; off > 0; off >>= 1) {
            t0 += __shfl_down(t0, off);
            t1 += __shfl_down(t1, off);
        }
        __shared__ float red[2][2];
        const int wave = tid >> 6, lane = tid & 63;
        if (act && lane == 0) { red[0][wave] = t0; red[1][wave] = t1; }
        __syncthreads();
        if (cgi == 0 && tid == 0) out[b * 2 + 0] = red[0][0] + red[0][1] + bp[0];
        if (cgi == 0 && tid == 1) out[b * 2 + 1] = red[1][0] + red[1][1] + bp[1];
    }
}

// ---------------------------------------------------------------------------
extern "C" void kernel_launch(void* const* d_in, const int* in_sizes, int n_in,
                              void* d_out, int out_size, void* d_ws, size_t ws_size,
                              hipStream_t stream) {
    const int*   sent = (const int*)d_in[0];
    const float* adj  = (const float*)d_in[1];
    const float* emb  = (const float*)d_in[2];
    const float* W1   = (const float*)d_in[3];
    const float* b1   = (const float*)d_in[4];
    const float* W2   = (const float*)d_in[5];
    const float* b2   = (const float*)d_in[6];
    const float* W3   = (const float*)d_in[7];
    const float* b3   = (const float*)d_in[8];
    const float* Wp   = (const float*)d_in[9];
    const float* bp   = (const float*)d_in[10];
    float* out = (float*)d_out;

    char* ws = (char*)d_ws;
    float*    h1     = (float*)ws;                              // 16 MiB
    float*    h2     = (float*)(ws + ((size_t)16 << 20));       // 16 MiB
    char*     base   = ws + ((size_t)32 << 20);
    float*    invdeg = (float*)base;                            // M f32
    int*      nnz    = (int*)(base + (size_t)M_ * 4);
    ushort_t* idxl   = (ushort_t*)(base + (size_t)M_ * 8);      // 8 MiB
    float*    pooled = (float*)(base + (size_t)M_ * 8 + (size_t)M_ * CAP_ * 2);
    int*      cnt    = (int*)(base + (size_t)M_ * 8 + (size_t)M_ * CAP_ * 2
                              + (size_t)B_ * H_ * 4);           // 64 ints

    k_pre<<<M_ / 4, 256, 0, stream>>>(adj, idxl, nnz, invdeg, cnt);

    void* args[] = {
        (void*)&sent, (void*)&emb,
        (void*)&W1, (void*)&b1, (void*)&W2, (void*)&b2,
        (void*)&W3, (void*)&b3, (void*)&Wp, (void*)&bp,
        (void*)&h1, (void*)&h2, (void*)&idxl, (void*)&nnz,
        (void*)&invdeg, (void*)&pooled, (void*)&cnt, (void*)&out
    };
    hipLaunchKernel((const void*)k_mega2, dim3(256), dim3(512), args, 0, stream);
}

// Round 11
// 269.413 us; speedup vs baseline: 1.5628x; 1.2104x over previous
//
#include <hip/hip_runtime.h>

typedef unsigned short ushort_t;
typedef unsigned long long ull_t;

#define B_ 64
#define S_ 512
#define E_ 256
#define H_ 128
#define M_ (B_ * S_)   // 32768 rows
#define CAP_ 128       // max neighbor slots

// ---------------------------------------------------------------------------
// K1: neighbor lists from binary adj (float4 reads) + invdeg = 1/(nnz+1)
// ---------------------------------------------------------------------------
__global__ void k_adjidx(const float* __restrict__ adj,
                         ushort_t* __restrict__ idxl,
                         int* __restrict__ nnz,
                         float* __restrict__ invdeg) {
    int row  = blockIdx.x * 4 + (threadIdx.x >> 6);
    int lane = threadIdx.x & 63;
    const float4* arow = (const float4*)(adj + (size_t)row * S_);
    ushort_t* dst = idxl + (size_t)row * CAP_;
    int total = 0;
    #pragma unroll
    for (int c = 0; c < 2; ++c) {
        float4 v = arow[c * 64 + lane];
        float f[4] = {v.x, v.y, v.z, v.w};
        #pragma unroll
        for (int j = 0; j < 4; ++j) {
            unsigned long long m = __ballot(f[j] != 0.0f);
            if (f[j] != 0.0f) {
                int pos = total + __popcll(m & ((1ull << lane) - 1ull));
                if (pos < CAP_) dst[pos] = (ushort_t)(c * 256 + lane * 4 + j);
            }
            total += __popcll(m);
        }
    }
    if (lane == 0) {
        nnz[row] = total < CAP_ ? total : CAP_;
        invdeg[row] = 1.0f / (float)(total + 1);
    }
}

// ---------------------------------------------------------------------------
// K2: fused layer — R2 geometry, 1024 threads (16 waves/CU, 4 waves/SIMD).
// 256 blocks = 64 batches x 4 col-groups of 32. LDS 106.5KB -> 1 block/CU.
//   Phase A: Ys[512][36] = X[b] @ W[cols]^T, 2x8 micro-tile (float2 X reads),
//            X k-major LDS double-buffer (one float4 load/thread/chunk).
//   Phase B: LDS gather, 128 rows in flight x 4 passes.
// Per-(row,col) FMA order and per-row gather order identical to R2
// (absmax-stable); pool regrouping is exact (fmax assoc/comm).
// ---------------------------------------------------------------------------
template <int K, bool GATHER, bool POOL>
__global__ __launch_bounds__(1024, 1)
void k_layer(const float* __restrict__ X, const int* __restrict__ sent,
             const float* __restrict__ emb, const float* __restrict__ W,
             const ushort_t* __restrict__ idxl, const int* __restrict__ nnz,
             const float* __restrict__ invdeg, const float* __restrict__ bias,
             float* __restrict__ out) {
    __shared__ __align__(16) float Ys[S_ * 36];      // 73728 B
    __shared__ __align__(16) float Xs[2][8 * S_];    // 32768 B
    __shared__ __align__(16) float Wsh[2][8 * 32];   // 2048 B

    const int tid = threadIdx.x;
    const int bid = blockIdx.x;
    const int xcd = bid & 7, slot = bid >> 3;
    const int b = xcd + 8 * (slot >> 2);
    const int cg = slot & 3;
    const int colBase = cg * 32;
    const int rowBase = b * S_;

    // ---- Phase A: GEMM ----
    // staging: thread owns row r0 = tid>>1, k-quarter kq (ONE float4/chunk)
    const int r0 = tid >> 1;              // 0..511
    const int kq = (tid & 1) * 4;         // 0 or 4
    const float* xp;
    if (GATHER) xp = emb + (size_t)sent[rowBase + r0] * K + kq;
    else        xp = X + (size_t)(rowBase + r0) * K + kq;

    const int wcol = (tid >> 1) & 31;     // used by tid<64
    const float* wp = W + (size_t)(colBase + wcol) * K + kq;

    // compute mapping: rows {2rp, 2rp+1}, cols c0..c0+7
    const int rp = tid >> 2;              // 0..255
    const int c0 = (tid & 3) * 8;

    float acc[2][8] = {};
    float4 g0;
    float4 wv = {0.f, 0.f, 0.f, 0.f};

    constexpr int NC = K / 8;

    // prologue: stage chunk 0
    g0 = *(const float4*)xp;
    if (tid < 64) wv = *(const float4*)wp;
    Xs[0][(kq + 0) * 512 + r0] = g0.x;
    Xs[0][(kq + 1) * 512 + r0] = g0.y;
    Xs[0][(kq + 2) * 512 + r0] = g0.z;
    Xs[0][(kq + 3) * 512 + r0] = g0.w;
    if (tid < 64) {
        Wsh[0][(kq + 0) * 32 + wcol] = wv.x;
        Wsh[0][(kq + 1) * 32 + wcol] = wv.y;
        Wsh[0][(kq + 2) * 32 + wcol] = wv.z;
        Wsh[0][(kq + 3) * 32 + wcol] = wv.w;
    }
    __syncthreads();

    #pragma unroll 1
    for (int c = 0; c < NC; ++c) {
        const int cur = c & 1;
        if (c + 1 < NC) {   // prefetch next chunk (global -> regs)
            g0 = *(const float4*)(xp + (c + 1) * 8);
            if (tid < 64) wv = *(const float4*)(wp + (c + 1) * 8);
        }
        #pragma unroll
        for (int k = 0; k < 8; ++k) {
            const float2 xa = *(const float2*)&Xs[cur][k * 512 + rp * 2];
            const float4 wa = *(const float4*)&Wsh[cur][k * 32 + c0];
            const float4 wb = *(const float4*)&Wsh[cur][k * 32 + c0 + 4];
            const float wv8[8] = {wa.x, wa.y, wa.z, wa.w, wb.x, wb.y, wb.z, wb.w};
            #pragma unroll
            for (int j = 0; j < 8; ++j) {
                acc[0][j] += xa.x * wv8[j];
                acc[1][j] += xa.y * wv8[j];
            }
        }
        if (c + 1 < NC) {   // regs -> other LDS buffer
            const int nb = cur ^ 1;
            Xs[nb][(kq + 0) * 512 + r0] = g0.x;
            Xs[nb][(kq + 1) * 512 + r0] = g0.y;
            Xs[nb][(kq + 2) * 512 + r0] = g0.z;
            Xs[nb][(kq + 3) * 512 + r0] = g0.w;
            if (tid < 64) {
                Wsh[nb][(kq + 0) * 32 + wcol] = wv.x;
                Wsh[nb][(kq + 1) * 32 + wcol] = wv.y;
                Wsh[nb][(kq + 2) * 32 + wcol] = wv.z;
                Wsh[nb][(kq + 3) * 32 + wcol] = wv.w;
            }
        }
        __syncthreads();
    }

    // epilogue: acc -> Ys slab
    #pragma unroll
    for (int i = 0; i < 2; ++i) {
        const int r = rp * 2 + i;
        *(float4*)&Ys[r * 36 + c0]     = make_float4(acc[i][0], acc[i][1], acc[i][2], acc[i][3]);
        *(float4*)&Ys[r * 36 + c0 + 4] = make_float4(acc[i][4], acc[i][5], acc[i][6], acc[i][7]);
    }
    __syncthreads();

    // ---- Phase B: LDS neighbor aggregation (+bias, invdeg, relu) ----
    const int rsub = tid >> 3;     // 0..127 rows in flight
    const int cc   = tid & 7;      // float4 chunk of the 32-col slab
    const float4* Ys4 = (const float4*)Ys;
    const float4 bv = *(const float4*)(bias + colBase + cc * 4);
    float4 pmax = {0.f, 0.f, 0.f, 0.f};

    int grow = rowBase + rsub;
    int n_cur = nnz[grow];
    float inv_cur = invdeg[grow];
    const ushort_t* il = idxl + (size_t)grow * CAP_;
    ull_t pk = *(const ull_t*)il;

    #pragma unroll 1
    for (int p = 0; p < 4; ++p) {
        const int r = p * 128 + rsub;
        int n_nxt = 0; float inv_nxt = 0.f; ull_t pk_nxt = 0;
        const ushort_t* il_nxt = il + 128 * CAP_;
        if (p < 3) {                       // prefetch next row's control data
            n_nxt = nnz[grow + 128];
            inv_nxt = invdeg[grow + 128];
            pk_nxt = *(const ull_t*)il_nxt;
        }
        float4 a = Ys4[r * 9 + cc];
        float4 a2 = {0.f, 0.f, 0.f, 0.f};
        const int n = n_cur;
        int i = 0;
        for (; i + 4 <= n; i += 4) {
            const ull_t pk_p = *(const ull_t*)(il + i + 4);
            const int t0 = (int)(pk & 0xffffu);
            const int t1 = (int)((pk >> 16) & 0xffffu);
            const int t2 = (int)((pk >> 32) & 0xffffu);
            const int t3 = (int)((pk >> 48) & 0xffffu);
            const float4 v0 = Ys4[t0 * 9 + cc];
            const float4 v1 = Ys4[t1 * 9 + cc];
            const float4 v2 = Ys4[t2 * 9 + cc];
            const float4 v3 = Ys4[t3 * 9 + cc];
            a.x += v0.x + v1.x;  a.y += v0.y + v1.y;
            a.z += v0.z + v1.z;  a.w += v0.w + v1.w;
            a2.x += v2.x + v3.x; a2.y += v2.y + v3.y;
            a2.z += v2.z + v3.z; a2.w += v2.w + v3.w;
            pk = pk_p;
        }
        for (; i < n; ++i) {
            const int t = il[i];
            const float4 v = Ys4[t * 9 + cc];
            a.x += v.x; a.y += v.y; a.z += v.z; a.w += v.w;
        }
        a.x += a2.x; a.y += a2.y; a.z += a2.z; a.w += a2.w;
        float4 o;
        o.x = fmaxf((a.x + 2.0f * bv.x) * inv_cur, 0.0f);
        o.y = fmaxf((a.y + 2.0f * bv.y) * inv_cur, 0.0f);
        o.z = fmaxf((a.z + 2.0f * bv.z) * inv_cur, 0.0f);
        o.w = fmaxf((a.w + 2.0f * bv.w) * inv_cur, 0.0f);
        if (!POOL) {
            ((float4*)(out + (size_t)(rowBase + r) * H_ + colBase))[cc] = o;
        } else {
            pmax.x = fmaxf(pmax.x, o.x); pmax.y = fmaxf(pmax.y, o.y);
            pmax.z = fmaxf(pmax.z, o.z); pmax.w = fmaxf(pmax.w, o.w);
        }
        grow += 128; il = il_nxt;
        n_cur = n_nxt; inv_cur = inv_nxt; pk = pk_nxt;
    }

    if (POOL) {
        // in-block pool over 128 row-groups (reuse Xs as scratch)
        float4* smax = (float4*)Xs;
        smax[rsub * 8 + cc] = pmax;            // 1024 entries
        __syncthreads();
        if (tid < 128) {
            const int g16 = tid >> 3, c2 = tid & 7;
            float4 m = smax[(g16 * 8 + 0) * 8 + c2];
            #pragma unroll
            for (int j = 1; j < 8; ++j) {
                const float4 v = smax[(g16 * 8 + j) * 8 + c2];
                m.x = fmaxf(m.x, v.x); m.y = fmaxf(m.y, v.y);
                m.z = fmaxf(m.z, v.z); m.w = fmaxf(m.w, v.w);
            }
            smax[1024 + g16 * 8 + c2] = m;
        }
        __syncthreads();
        if (tid < 8) {
            float4 m = smax[1024 + tid];
            #pragma unroll
            for (int g = 1; g < 16; ++g) {
                const float4 v = smax[1024 + g * 8 + tid];
                m.x = fmaxf(m.x, v.x); m.y = fmaxf(m.y, v.y);
                m.z = fmaxf(m.z, v.z); m.w = fmaxf(m.w, v.w);
            }
            ((float4*)(out + (size_t)b * H_ + colBase))[tid] = m;
        }
    }
}

// ---------------------------------------------------------------------------
// K3: logits[b,c] = pooled[b,:] . Wp[c,:] + bp[c]   (pooled is [64][128])
// ---------------------------------------------------------------------------
__global__ void k_final(const float* __restrict__ pooled,
                        const float* __restrict__ Wp,
                        const float* __restrict__ bp,
                        float* __restrict__ out) {
    int b = blockIdx.x, j = threadIdx.x;  // 128 threads
    float m = pooled[(size_t)b * H_ + j];
    float t0 = m * Wp[j];
    float t1 = m * Wp[H_ + j];
    #pragma unroll
    for (int off = 32; off > 0; off >>= 1) {
        t0 += __shfl_down(t0, off);
        t1 += __shfl_down(t1, off);
    }
    __shared__ float red[2][2];
    int wave = j >> 6, lane = j & 63;
    if (lane == 0) { red[0][wave] = t0; red[1][wave] = t1; }
    __syncthreads();
    if (j == 0) out[b * 2 + 0] = red[0][0] + red[0][1] + bp[0];
    if (j == 1) out[b * 2 + 1] = red[1][0] + red[1][1] + bp[1];
}

// ---------------------------------------------------------------------------
extern "C" void kernel_launch(void* const* d_in, const int* in_sizes, int n_in,
                              void* d_out, int out_size, void* d_ws, size_t ws_size,
                              hipStream_t stream) {
    const int*   sent = (const int*)d_in[0];
    const float* adj  = (const float*)d_in[1];
    const float* emb  = (const float*)d_in[2];
    const float* W1   = (const float*)d_in[3];
    const float* b1   = (const float*)d_in[4];
    const float* W2   = (const float*)d_in[5];
    const float* b2   = (const float*)d_in[6];
    const float* W3   = (const float*)d_in[7];
    const float* b3   = (const float*)d_in[8];
    const float* Wp   = (const float*)d_in[9];
    const float* bp   = (const float*)d_in[10];
    float* out = (float*)d_out;

    char* ws = (char*)d_ws;
    float*    h1     = (float*)ws;                              // 16 MiB
    float*    h2     = (float*)(ws + ((size_t)16 << 20));       // 16 MiB
    char*     base   = ws + ((size_t)32 << 20);
    float*    invdeg = (float*)base;                            // M f32
    int*      nnz    = (int*)(base + (size_t)M_ * 4);
    ushort_t* idxl   = (ushort_t*)(base + (size_t)M_ * 8);      // 8 MiB
    float*    pooled = (float*)(base + (size_t)M_ * 8 + (size_t)M_ * CAP_ * 2);

    k_adjidx<<<M_ / 4, 256, 0, stream>>>(adj, idxl, nnz, invdeg);

    k_layer<E_, true,  false><<<256, 1024, 0, stream>>>(nullptr, sent, emb, W1, idxl, nnz, invdeg, b1, h1);
    k_layer<H_, false, false><<<256, 1024, 0, stream>>>(h1, nullptr, nullptr, W2, idxl, nnz, invdeg, b2, h2);
    k_layer<H_, false, true ><<<256, 1024, 0, stream>>>(h2, nullptr, nullptr, W3, idxl, nnz, invdeg, b3, pooled);

    k_final<<<B_, H_, 0, stream>>>(pooled, Wp, bp, out);
}